// Round 3
// baseline (213.268 us; speedup 1.0000x reference)
//
#include <hip/hip_runtime.h>

// Problem constants (from setup_inputs): B=16, C=3, H=W=512, labels 16*1*30*30.
#define NCH        48                 // 16*3 channels
#define CH_ELEMS   (512*512)          // 262144 elements per channel
#define BLK_PER_CH 32
#define NBLOCKS    (NCH * BLK_PER_CH) // 1536
#define CHUNK4     (CH_ELEMS / BLK_PER_CH / 4)   // 2048 float4 per block
#define NTHREADS   256

// Harness contract: d_ws is re-poisoned to 0xAA bytes before EVERY launch,
// so the ticket counter deterministically starts at 0xAAAAAAAA.
#define POISON32   0xAAAAAAAAu

// ws layout: float part_sum[1536]; uint part_nz[1536]; uint ticket.

__global__ __launch_bounds__(NTHREADS) void genloss_fused(
    const float4* __restrict__ out_img,
    const float4* __restrict__ tgt_img,
    const float*  __restrict__ labels, int n_labels,
    const int*    __restrict__ epoch_p,
    float* __restrict__ part_sum,
    unsigned int* __restrict__ part_nz,
    unsigned int* __restrict__ ticket,
    float* __restrict__ out)
{
    const long base4 = (long)blockIdx.x * CHUNK4;

    float lsum = 0.0f;
    int   lnz  = 0;
    #pragma unroll
    for (int i = threadIdx.x; i < CHUNK4; i += NTHREADS) {
        float4 a = out_img[base4 + i];
        float4 b = tgt_img[base4 + i];
        lsum += fabsf(a.x - b.x) + fabsf(a.y - b.y)
              + fabsf(a.z - b.z) + fabsf(a.w - b.w);
        lnz  |= (b.x != 0.0f) | (b.y != 0.0f) | (b.z != 0.0f) | (b.w != 0.0f);
    }

    // wave-64 reduction
    #pragma unroll
    for (int off = 32; off > 0; off >>= 1) {
        lsum += __shfl_down(lsum, off, 64);
        lnz  |= __shfl_down(lnz,  off, 64);
    }

    __shared__ float ssum[NTHREADS / 64];
    __shared__ int   snz [NTHREADS / 64];
    __shared__ int   is_last;
    const int wave = threadIdx.x >> 6;
    if ((threadIdx.x & 63) == 0) { ssum[wave] = lsum; snz[wave] = lnz; }
    __syncthreads();

    if (threadIdx.x == 0) {
        float t = 0.0f; int nz = 0;
        #pragma unroll
        for (int w = 0; w < NTHREADS / 64; ++w) { t += ssum[w]; nz |= snz[w]; }
        part_sum[blockIdx.x] = t;
        part_nz [blockIdx.x] = (unsigned int)nz;
        __threadfence();                               // release partials (device scope)
        unsigned int old = atomicAdd(ticket, 1u);      // device-scope by default
        is_last = (old == POISON32 + (NBLOCKS - 1)) ? 1 : 0;
    }
    __syncthreads();
    if (!is_last) return;

    // ---- last block: final reduction ----
    __threadfence();                                   // acquire other blocks' partials

    __shared__ float chsum[NCH];
    __shared__ int   chnz [NCH];
    if (threadIdx.x < NCH) {
        const int ch = threadIdx.x;
        float t = 0.0f; unsigned int nz = 0;
        #pragma unroll
        for (int j = 0; j < BLK_PER_CH; ++j) {
            t  += part_sum[ch * BLK_PER_CH + j];
            nz |= part_nz [ch * BLK_PER_CH + j];
        }
        chsum[ch] = t;
        chnz [ch] = (int)(nz != 0u);
    }

    float l = 0.0f;
    for (int i = threadIdx.x; i < n_labels; i += NTHREADS) l += labels[i];
    #pragma unroll
    for (int off = 32; off > 0; off >>= 1) l += __shfl_down(l, off, 64);

    __shared__ float lsumw[NTHREADS / 64];
    if ((threadIdx.x & 63) == 0) lsumw[wave] = l;
    __syncthreads();

    if (threadIdx.x == 0) {
        float labsum = 0.0f;
        #pragma unroll
        for (int w = 0; w < NTHREADS / 64; ++w) labsum += lsumw[w];

        float image_loss = 0.0f;
        for (int b = 0; b < 16; ++b) {
            float tot = 0.0f, cnt = 0.0f;
            for (int c = 0; c < 3; ++c) {
                const int ch = b * 3 + c;
                const float valid = chnz[ch] ? 1.0f : 0.0f;
                tot += (chsum[ch] * (1.0f / (float)CH_ELEMS)) * valid;
                cnt += valid;
            }
            image_loss += (cnt > 0.0f) ? tot / fmaxf(cnt, 1.0f) : 0.0f;
        }
        image_loss *= (1.0f / 16.0f);

        const float adv   = -(labsum / (float)n_labels);
        const float epoch = (float)epoch_p[0];
        out[0] = image_loss + 0.01f * adv / (epoch + 1.0f);
    }
}

extern "C" void kernel_launch(void* const* d_in, const int* in_sizes, int n_in,
                              void* d_out, int out_size, void* d_ws, size_t ws_size,
                              hipStream_t stream) {
    const float* labels  = (const float*)d_in[0];
    const float4* out_im = (const float4*)d_in[1];
    const float4* tgt_im = (const float4*)d_in[2];
    const int*   epoch_p = (const int*)d_in[3];
    const int n_labels   = in_sizes[0];

    float*        part_sum = (float*)d_ws;
    unsigned int* part_nz  = (unsigned int*)((char*)d_ws + NBLOCKS * sizeof(float));
    unsigned int* ticket   = (unsigned int*)((char*)d_ws + 2 * NBLOCKS * sizeof(float));

    genloss_fused<<<NBLOCKS, NTHREADS, 0, stream>>>(
        out_im, tgt_im, labels, n_labels, epoch_p,
        part_sum, part_nz, ticket, (float*)d_out);
}

// Round 4
// 145.824 us; speedup vs baseline: 1.4625x; 1.4625x over previous
//
#include <hip/hip_runtime.h>

// Problem constants (from setup_inputs): B=16, C=3, H=W=512, labels 16*1*30*30.
#define NCH        48                 // 16*3 channels
#define CH_ELEMS   (512*512)          // 262144 elements per channel
#define BLK_PER_CH 32
#define NBLOCKS    (NCH * BLK_PER_CH) // 1536
#define CHUNK4     (CH_ELEMS / BLK_PER_CH / 4)   // 2048 float4 per block
#define NTHREADS   256

// ws layout: float part_sum[1536]; uint part_nz[1536].  Every slot is written
// unconditionally every launch -> no zero-init needed (ws arrives poisoned).
// NOTE (R3 post-mortem): do NOT fuse via last-block-done here — per-block
// device-scope fences (buffer_wbl2) across 8 non-coherent XCD L2s cost ~100 µs,
// far more than the ~4 µs second dispatch they'd save.

__global__ __launch_bounds__(NTHREADS) void chan_reduce(
    const float4* __restrict__ out_img,
    const float4* __restrict__ tgt_img,
    float* __restrict__ part_sum,
    unsigned int* __restrict__ part_nz)
{
    const long base4 = (long)blockIdx.x * CHUNK4;

    float lsum = 0.0f;
    int   lnz  = 0;
    #pragma unroll
    for (int i = threadIdx.x; i < CHUNK4; i += NTHREADS) {
        float4 a = out_img[base4 + i];
        float4 b = tgt_img[base4 + i];
        lsum += fabsf(a.x - b.x) + fabsf(a.y - b.y)
              + fabsf(a.z - b.z) + fabsf(a.w - b.w);
        lnz  |= (b.x != 0.0f) | (b.y != 0.0f) | (b.z != 0.0f) | (b.w != 0.0f);
    }

    // wave-64 reduction
    #pragma unroll
    for (int off = 32; off > 0; off >>= 1) {
        lsum += __shfl_down(lsum, off, 64);
        lnz  |= __shfl_down(lnz,  off, 64);
    }

    __shared__ float ssum[NTHREADS / 64];
    __shared__ int   snz [NTHREADS / 64];
    const int wave = threadIdx.x >> 6;
    if ((threadIdx.x & 63) == 0) { ssum[wave] = lsum; snz[wave] = lnz; }
    __syncthreads();
    if (threadIdx.x == 0) {
        float t = 0.0f; int nz = 0;
        #pragma unroll
        for (int w = 0; w < NTHREADS / 64; ++w) { t += ssum[w]; nz |= snz[w]; }
        part_sum[blockIdx.x] = t;                 // plain store, no init needed
        part_nz [blockIdx.x] = (unsigned int)nz;
    }
}

__global__ __launch_bounds__(NTHREADS) void finalize(
    const float* __restrict__ labels, int n_labels,
    const float* __restrict__ part_sum,
    const unsigned int* __restrict__ part_nz,
    const int* __restrict__ epoch_p,
    float* __restrict__ out)
{
    __shared__ float chsum[NCH];
    __shared__ int   chnz [NCH];

    // Threads 0..47: fold the 32 partials of one channel.
    if (threadIdx.x < NCH) {
        const int ch = threadIdx.x;
        float t = 0.0f; unsigned int nz = 0;
        #pragma unroll
        for (int j = 0; j < BLK_PER_CH; ++j) {
            t  += part_sum[ch * BLK_PER_CH + j];
            nz |= part_nz [ch * BLK_PER_CH + j];
        }
        chsum[ch] = t;
        chnz [ch] = (int)(nz != 0u);
    }

    // All threads: reduce the labels.
    float l = 0.0f;
    for (int i = threadIdx.x; i < n_labels; i += NTHREADS) l += labels[i];
    #pragma unroll
    for (int off = 32; off > 0; off >>= 1) l += __shfl_down(l, off, 64);

    __shared__ float lsumw[NTHREADS / 64];
    const int wave = threadIdx.x >> 6;
    if ((threadIdx.x & 63) == 0) lsumw[wave] = l;
    __syncthreads();

    if (threadIdx.x == 0) {
        float lsum = 0.0f;
        #pragma unroll
        for (int w = 0; w < NTHREADS / 64; ++w) lsum += lsumw[w];

        float image_loss = 0.0f;
        for (int b = 0; b < 16; ++b) {
            float tot = 0.0f, cnt = 0.0f;
            for (int c = 0; c < 3; ++c) {
                const int ch = b * 3 + c;
                const float valid = chnz[ch] ? 1.0f : 0.0f;
                tot += (chsum[ch] * (1.0f / (float)CH_ELEMS)) * valid;
                cnt += valid;
            }
            image_loss += (cnt > 0.0f) ? tot / fmaxf(cnt, 1.0f) : 0.0f;
        }
        image_loss *= (1.0f / 16.0f);

        const float adv   = -(lsum / (float)n_labels);
        const float epoch = (float)epoch_p[0];
        out[0] = image_loss + 0.01f * adv / (epoch + 1.0f);
    }
}

extern "C" void kernel_launch(void* const* d_in, const int* in_sizes, int n_in,
                              void* d_out, int out_size, void* d_ws, size_t ws_size,
                              hipStream_t stream) {
    const float* labels  = (const float*)d_in[0];
    const float4* out_im = (const float4*)d_in[1];
    const float4* tgt_im = (const float4*)d_in[2];
    const int*   epoch_p = (const int*)d_in[3];
    const int n_labels   = in_sizes[0];

    float*        part_sum = (float*)d_ws;
    unsigned int* part_nz  = (unsigned int*)((char*)d_ws + NBLOCKS * sizeof(float));

    chan_reduce<<<NBLOCKS, NTHREADS, 0, stream>>>(out_im, tgt_im, part_sum, part_nz);
    finalize<<<1, NTHREADS, 0, stream>>>(labels, n_labels, part_sum, part_nz,
                                         epoch_p, (float*)d_out);
}